// Round 2
// baseline (2030.544 us; speedup 1.0000x reference)
//
#include <hip/hip_runtime.h>
#include <stdint.h>

#define B_ 32
#define N_ 2048
#define D_ 128
#define TQ 16
#define SCALE 0.08838834764831845f
#define MASK_FILL -65504.0f

typedef __attribute__((ext_vector_type(8))) short short8;
typedef __attribute__((ext_vector_type(4))) float f32x4;

// fp32 -> bf16 bits, round-to-nearest-even (finite inputs only)
static __device__ __forceinline__ short f2bf(float f) {
    unsigned u = __builtin_bit_cast(unsigned, f);
    u += 0x7FFFu + ((u >> 16) & 1u);
    return (short)(u >> 16);
}

// Kernel 1: S = Q K^T * scale, mask, softmax, write normalized P (attn) fp32.
// One workgroup = 16 query rows x all 2048 key cols of one batch.
__global__ __launch_bounds__(256)
void attn_softmax_kernel(const float* __restrict__ Q, const float* __restrict__ K,
                         const int* __restrict__ mask, float* __restrict__ attn) {
    extern __shared__ float Sc[];   // [TQ][N_] fp32 scores = 64 KB

    const int tid  = threadIdx.x;
    const int b    = blockIdx.y;
    const int row0 = blockIdx.x * TQ;
    const int lane = tid & 63;
    const int w    = tid >> 6;       // wave 0..3
    const int quad = lane >> 4;      // 0..3
    const int l16  = lane & 15;

    const size_t kvbase = (size_t)b * N_ * D_;

    // A-fragments (Q) in registers: A[m=l16][k = 32*kt + quad*8 + j]
    short8 aq[4];
    {
        const float* qp = Q + kvbase + (size_t)(row0 + l16) * D_ + quad * 8;
        #pragma unroll
        for (int kt = 0; kt < 4; ++kt) {
            #pragma unroll
            for (int j = 0; j < 8; ++j) aq[kt][j] = f2bf(qp[kt * 32 + j]);
        }
    }

    // Phase 1: S tiles. Each wave does col-tiles ct = w, w+4, ...
    for (int i = 0; i < 32; ++i) {
        const int c0 = (w + 4 * i) * 16;
        f32x4 acc = {0.f, 0.f, 0.f, 0.f};
        #pragma unroll
        for (int kt = 0; kt < 4; ++kt) {
            // B[k][n=l16] = K[c0+l16][k], k = 32*kt + quad*8 + j
            const float* kp = K + kvbase + (size_t)(c0 + l16) * D_ + kt * 32 + quad * 8;
            short8 bf;
            #pragma unroll
            for (int j = 0; j < 8; ++j) bf[j] = f2bf(kp[j]);
            acc = __builtin_amdgcn_mfma_f32_16x16x32_bf16(aq[kt], bf, acc, 0, 0, 0);
        }
        // C/D layout: col = lane&15, row = quad*4 + r
        const int* mrow = mask + ((size_t)b * N_ + row0) * N_ + c0 + l16;
        #pragma unroll
        for (int r = 0; r < 4; ++r) {
            const int row = quad * 4 + r;
            const float s = acc[r] * SCALE;
            const int mv = mrow[(size_t)row * N_];
            Sc[row * N_ + c0 + l16] = mv ? s : MASK_FILL;
        }
    }
    __syncthreads();

    // Phase 2: row softmax. 16 threads per row (contiguous tid -> same wave).
    {
        const int r = tid >> 4;
        const int l = tid & 15;
        float m = -INFINITY;
        for (int c = l; c < N_; c += 16) m = fmaxf(m, Sc[r * N_ + c]);
        #pragma unroll
        for (int off = 8; off >= 1; off >>= 1) m = fmaxf(m, __shfl_xor(m, off, 16));
        float sum = 0.f;
        for (int c = l; c < N_; c += 16) {
            const float e = __expf(Sc[r * N_ + c] - m);
            Sc[r * N_ + c] = e;
            sum += e;
        }
        #pragma unroll
        for (int off = 8; off >= 1; off >>= 1) sum += __shfl_xor(sum, off, 16);
        const float inv = 1.f / sum;

        // normalized write, float4-coalesced
        float* ao = attn + ((size_t)b * N_ + row0 + r) * N_;
        for (int c = l * 4; c < N_; c += 64) {
            f32x4 v = *(const f32x4*)&Sc[r * N_ + c];
            v[0] *= inv; v[1] *= inv; v[2] *= inv; v[3] *= inv;
            *(f32x4*)&ao[c] = v;
        }
    }
}

// Kernel 2: O = P V. One workgroup = 16 output rows of one batch.
__global__ __launch_bounds__(256)
void attn_pv_kernel(const float* __restrict__ attn, const float* __restrict__ V,
                    float* __restrict__ ctx) {
    const int tid  = threadIdx.x;
    const int b    = blockIdx.y;
    const int row0 = blockIdx.x * TQ;
    const int lane = tid & 63;
    const int w    = tid >> 6;
    const int quad = lane >> 4;
    const int l16  = lane & 15;

    const size_t kvbase = (size_t)b * N_ * D_;
    const int n0a = w * 16;
    const int n0b = n0a + 64;

    f32x4 acc0 = {0.f, 0.f, 0.f, 0.f};
    f32x4 acc1 = {0.f, 0.f, 0.f, 0.f};

    const float* prow = attn + ((size_t)b * N_ + row0 + l16) * N_;

    for (int kk = 0; kk < N_; kk += 32) {
        // A[m=l16][k = kk + quad*8 + j] from normalized P (fp32 global)
        const float* pp = prow + kk + quad * 8;
        short8 a;
        #pragma unroll
        for (int j = 0; j < 8; ++j) a[j] = f2bf(pp[j]);

        // B[k][n=l16] = V[kk+quad*8+j][n0 + l16]
        short8 b0, b1;
        #pragma unroll
        for (int j = 0; j < 8; ++j) {
            const float* vp = V + kvbase + (size_t)(kk + quad * 8 + j) * D_;
            b0[j] = f2bf(vp[n0a + l16]);
            b1[j] = f2bf(vp[n0b + l16]);
        }
        acc0 = __builtin_amdgcn_mfma_f32_16x16x32_bf16(a, b0, acc0, 0, 0, 0);
        acc1 = __builtin_amdgcn_mfma_f32_16x16x32_bf16(a, b1, acc1, 0, 0, 0);
    }

    float* co = ctx + ((size_t)b * N_ + row0) * D_;
    #pragma unroll
    for (int r = 0; r < 4; ++r) {
        const int row = quad * 4 + r;
        co[(size_t)row * D_ + n0a + l16] = acc0[r];
        co[(size_t)row * D_ + n0b + l16] = acc1[r];
    }
}

extern "C" void kernel_launch(void* const* d_in, const int* in_sizes, int n_in,
                              void* d_out, int out_size, void* d_ws, size_t ws_size,
                              hipStream_t stream) {
    const float* Q    = (const float*)d_in[0];
    const float* K    = (const float*)d_in[1];
    const float* V    = (const float*)d_in[2];
    const int*   mask = (const int*)d_in[3];

    float* out  = (float*)d_out;
    float* ctx  = out;                         // [B, N, D]
    float* attn = out + (size_t)B_ * N_ * D_;  // [B, N, N]

    dim3 grid(N_ / TQ, B_, 1);
    dim3 block(256, 1, 1);

    attn_softmax_kernel<<<grid, block, TQ * N_ * sizeof(float), stream>>>(Q, K, mask, attn);
    attn_pv_kernel<<<grid, block, 0, stream>>>(attn, V, ctx);
}